// Round 12
// baseline (273.920 us; speedup 1.0000x reference)
//
#include <hip/hip_runtime.h>

// MultiHeadedAttention (B=8, S=1024, D=512, H=8, DK=DV=64), f32 in/out.
// r19: r18's occupancy lever (64 q-rows/block, grid 16x8x8 -> 3 blocks/CU,
// 3 waves/SIMD) with the race-suspect counted vmcnt REMOVED: unconditional
// vmcnt(0) top drain (r11's proven scheme; counted wait measured null in r15
// anyway). No sched_barrier pins. GEMMs = r17 (proven 264µs total).

typedef unsigned short u16;
typedef unsigned u32;
typedef u16 u16x4 __attribute__((ext_vector_type(4)));
typedef u16 u16x8 __attribute__((ext_vector_type(8)));
typedef short s16x8 __attribute__((ext_vector_type(8)));
typedef u32 u32x2 __attribute__((ext_vector_type(2)));
typedef float f32x4 __attribute__((ext_vector_type(4)));

#define SB 1024
#define DD 512
// -1e9 * log2(e): mask penalty in exp2 domain
#define NEGC2 (-1.4426950408889634e9f)
// 0.125 * log2(e): Q scale in exp2 domain
#define QSCALE (0.18033688011112443f)
#define THR 11.5f

__device__ __forceinline__ u16 f2bf(float f) {
    unsigned u = __float_as_uint(f);
    u += 0x7FFFu + ((u >> 16) & 1u);
    return (u16)(u >> 16);
}

// HW packed f32->bf16 (RNE, same rounding as f2bf): lo in [15:0], hi in [31:16]
__device__ __forceinline__ u32 pkbf(float lo, float hi) {
    u32 r;
    asm("v_cvt_pk_bf16_f32 %0, %1, %2" : "=v"(r) : "v"(lo), "v"(hi));
    return r;
}

// global -> LDS direct copy, 16B per lane (wave-uniform LDS base + lane*16)
__device__ __forceinline__ void gll16(const u16* g, u16* l) {
    __builtin_amdgcn_global_load_lds(
        (const __attribute__((address_space(1))) void*)g,
        (__attribute__((address_space(3))) void*)l, 16, 0, 0);
}

// DPP cross-lane (16-lane row) reduce — pure VALU, no LDS pipe.
template<int CTRL>
__device__ __forceinline__ float dppf(float x) {
    return __int_as_float(__builtin_amdgcn_mov_dpp(__float_as_int(x), CTRL, 0xF, 0xF, true));
}
__device__ __forceinline__ float row16_max(float x) {
    x = fmaxf(x, dppf<0xB1>(x));
    x = fmaxf(x, dppf<0x4E>(x));
    x = fmaxf(x, dppf<0x141>(x));
    x = fmaxf(x, dppf<0x140>(x));
    return x;
}
__device__ __forceinline__ float row16_sum(float x) {
    x += dppf<0xB1>(x);
    x += dppf<0x4E>(x);
    x += dppf<0x141>(x);
    x += dppf<0x140>(x);
    return x;
}

// ---------------------------------------------------------------------------
// GEMM body: C[m][n] = (sum_k X[m][k]*W[n][k] + bias[n]) * scale
// Tile BM(M)x128(N), BK=64, 4 waves (wave-tile BM/4 x 128). Double-buffered
// LDS, pitch 64 + XOR swizzle (col ^= (row&7)<<3). ONE barrier/iter.
// XCD swizzle for L2 reuse of X slabs. cvt_pk staging conversion.
// ---------------------------------------------------------------------------
template<bool XF32, bool OUTF32, int BM>
__device__ __forceinline__ void gemm_body(
    const void* __restrict__ Xv, const float* __restrict__ W,
    const float* __restrict__ bias, void* __restrict__ Cv,
    int M, int N, int K, float scale)
{
    __shared__ __align__(16) u16 As[2][BM][64];
    __shared__ __align__(16) u16 Bs[2][128][64];
    const int tid  = threadIdx.x;
    const int lane = tid & 63, wave = tid >> 6;
    const int l15 = lane & 15, lq = lane >> 4;

    const int l   = blockIdx.x + gridDim.x * blockIdx.y;
    const int xcd = l & 7, j = l >> 3;
    const int nb  = N / 128;
    const int m0  = (xcd * (M / BM / 8) + (j / nb)) * BM;
    const int n0  = (j % nb) * 128;

    constexpr int XI32 = BM / 16;   // f32-X staging passes (16 rows each)
    constexpr int XI16 = BM / 32;   // bf16-X staging passes (32 rows each)
    constexpr int MT   = BM / 64;   // 16-row MFMA tiles per wave

    // staging index precompute
    int xr32[XI32], xc32_, xr16[XI16], xc16_, wr_[8], wc_;
    xc32_ = (tid & 15) * 4;
    xc16_ = (tid & 7) * 8;
    wc_   = (tid & 15) * 4;
    #pragma unroll
    for (int i = 0; i < XI32; ++i) xr32[i] = i * 16 + (tid >> 4);
    #pragma unroll
    for (int i = 0; i < XI16; ++i) xr16[i] = i * 32 + (tid >> 3);
    #pragma unroll
    for (int i = 0; i < 8; ++i)    wr_[i]  = i * 16 + (tid >> 4);

    f32x4 xa32[XI32];  u16x8 xa16[XI16];  f32x4 wa[8];
    auto load_slab = [&](int k0) {
        if (XF32) {
            #pragma unroll
            for (int i = 0; i < XI32; ++i)
                xa32[i] = *(const f32x4*)((const float*)Xv + (size_t)(m0 + xr32[i]) * K + k0 + xc32_);
        } else {
            #pragma unroll
            for (int i = 0; i < XI16; ++i)
                xa16[i] = *(const u16x8*)((const u16*)Xv + (size_t)(m0 + xr16[i]) * K + k0 + xc16_);
        }
        #pragma unroll
        for (int i = 0; i < 8; ++i)
            wa[i] = *(const f32x4*)(W + (size_t)(n0 + wr_[i]) * K + k0 + wc_);
    };
    auto write_lds = [&](int buf) {
        if (XF32) {
            #pragma unroll
            for (int i = 0; i < XI32; ++i) {
                u32x2 t;
                t[0] = pkbf(xa32[i][0], xa32[i][1]);
                t[1] = pkbf(xa32[i][2], xa32[i][3]);
                *(u32x2*)&As[buf][xr32[i]][xc32_ ^ ((xr32[i] & 7) << 3)] = t;
            }
        } else {
            #pragma unroll
            for (int i = 0; i < XI16; ++i)
                *(u16x8*)&As[buf][xr16[i]][xc16_ ^ ((xr16[i] & 7) << 3)] = xa16[i];
        }
        #pragma unroll
        for (int i = 0; i < 8; ++i) {
            u32x2 t;
            t[0] = pkbf(wa[i][0], wa[i][1]);
            t[1] = pkbf(wa[i][2], wa[i][3]);
            *(u32x2*)&Bs[buf][wr_[i]][wc_ ^ ((wr_[i] & 7) << 3)] = t;
        }
    };

    f32x4 acc[MT][8] = {};
    load_slab(0);
    const int steps = K / 64;
    for (int kt = 0; kt < steps; ++kt) {
        const int buf = kt & 1;
        write_lds(buf);            // slab kt (regs from iter kt-1); buffer unread this iter
        __syncthreads();
        if (kt + 1 < steps) load_slab((kt + 1) * 64);

        #pragma unroll
        for (int ks = 0; ks < 2; ++ks) {
            const int kc = ks * 32 + lq * 8;
            s16x8 af[MT], bf[8];
            #pragma unroll
            for (int mt = 0; mt < MT; ++mt) {
                const int ar = wave * (BM / 4) + mt * 16 + l15;
                af[mt] = *(const s16x8*)&As[buf][ar][kc ^ ((ar & 7) << 3)];
            }
            #pragma unroll
            for (int nt = 0; nt < 8; ++nt) {
                const int br = nt * 16 + l15;
                bf[nt] = *(const s16x8*)&Bs[buf][br][kc ^ ((br & 7) << 3)];
            }
            #pragma unroll
            for (int mt = 0; mt < MT; ++mt)
                #pragma unroll
                for (int nt = 0; nt < 8; ++nt)
                    acc[mt][nt] = __builtin_amdgcn_mfma_f32_16x16x32_bf16(
                        af[mt], bf[nt], acc[mt][nt], 0, 0, 0);
        }
    }

    float bb[8];
    #pragma unroll
    for (int nt = 0; nt < 8; ++nt) bb[nt] = bias[n0 + nt * 16 + l15];
    #pragma unroll
    for (int mt = 0; mt < MT; ++mt) {
        #pragma unroll
        for (int r = 0; r < 4; ++r) {
            const size_t row = (size_t)(m0 + wave * (BM / 4) + mt * 16 + lq * 4 + r);
            #pragma unroll
            for (int nt = 0; nt < 8; ++nt) {
                float v = (acc[mt][nt][r] + bb[nt]) * scale;
                const size_t col = n0 + nt * 16 + l15;
                if (OUTF32) ((float*)Cv)[row * N + col] = v;
                else        ((u16*)Cv)[row * N + col] = f2bf(v);
            }
        }
    }
}

struct QKVParams {
    const float *X0, *X1, *X2;
    const float *W0, *W1, *W2;
    const float *b0, *b1, *b2;
    u16 *C0, *C1, *C2;
};

// fused Q/K/V projections: blockIdx.z selects the sub-GEMM
__global__ __launch_bounds__(256, 2) void qkv_gemm(QKVParams p) {
    const int z = blockIdx.z;
    const float* X = (z == 0) ? p.X0 : (z == 1) ? p.X1 : p.X2;
    const float* W = (z == 0) ? p.W0 : (z == 1) ? p.W1 : p.W2;
    const float* b = (z == 0) ? p.b0 : (z == 1) ? p.b1 : p.b2;
    u16* C = (z == 0) ? p.C0 : (z == 1) ? p.C1 : p.C2;
    const float scale = (z == 0) ? QSCALE : 1.0f;   // Q in exp2 domain
    gemm_body<true, false, 128>(X, W, b, C, 8 * SB, DD, DD, scale);
}

// 64x128 tile: 512 blocks, 48KB LDS -> up to 3 blocks/CU
__global__ __launch_bounds__(256, 2) void out_gemm(
    const u16* __restrict__ X, const float* __restrict__ W,
    const float* __restrict__ bias, float* __restrict__ C) {
    gemm_body<false, true, 64>(X, W, bias, C, 8 * SB, DD, DD, 1.0f);
}

// ---------------------------------------------------------------------------
// repack: K,V (bf16, [b*SB+tok][h*64+d] row-major) -> fragment-linear layouts.
// Frag tile = 512 elems (64 lanes x 8): offset ((bh*16+kb)*8 + nt*2+ks)*512 + lane*8.
//   Kf elem(lane,e) = K[tok=kb*64+nt*16+(lane&15)][d =ks*32+(lane>>4)*8+e]
//   Vf elem(lane,e) = V[tok=kb*64+ks*32+(lane>>4)*8+e][dv=nt*16+(lane&15)]
// ---------------------------------------------------------------------------
__global__ __launch_bounds__(256) void repack_kernel(
    const u16* __restrict__ Kn, const u16* __restrict__ Vn,
    u16* __restrict__ Kf, u16* __restrict__ Vf)
{
    __shared__ u16 Ls[2][64][72];
    const int t = threadIdx.x;
    const int kb = blockIdx.x;          // 0..15
    const int bh = blockIdx.y;          // 0..63
    const int b = bh >> 3, h = bh & 7;
    const int r = t >> 2, c = (t & 3) * 16;

    const size_t srow = (size_t)(b * SB + kb * 64 + r) * DD + h * 64 + c;
    *(u16x8*)&Ls[0][r][c]     = *(const u16x8*)(Kn + srow);
    *(u16x8*)&Ls[0][r][c + 8] = *(const u16x8*)(Kn + srow + 8);
    *(u16x8*)&Ls[1][r][c]     = *(const u16x8*)(Vn + srow);
    *(u16x8*)&Ls[1][r][c + 8] = *(const u16x8*)(Vn + srow + 8);
    __syncthreads();

    const int lane = t & 63, w = t >> 6;
    const int l15 = lane & 15, lq = lane >> 4;
    const size_t tb = ((size_t)bh * 16 + kb) * 4096 + lane * 8;
    #pragma unroll
    for (int i = 0; i < 2; ++i) {
        const int t2 = w * 2 + i;          // 0..7 = nt*2+ks
        const int nt = t2 >> 1, ks = t2 & 1;
        u16x8 ko = *(const u16x8*)&Ls[0][nt * 16 + l15][ks * 32 + lq * 8];
        *(u16x8*)(Kf + tb + t2 * 512) = ko;
        u16x8 vo;
        #pragma unroll
        for (int e = 0; e < 8; ++e) vo[e] = Ls[1][ks * 32 + lq * 8 + e][nt * 16 + l15];
        *(u16x8*)(Vf + tb + t2 * 512) = vo;
    }
}

// ---------------------------------------------------------------------------
// Flash attention. Grid (16,8,8) = 1024 blocks, 256 thr / 4 waves; 64
// q-rows/block, wave w owns 16 rows (ONE 16-row MFMA tile). 3 blocks/CU
// (LDS-capped) = 3 waves/SIMD. K/V staged per-block in LDS via
// global_load_lds from fragment-linear Kf/Vf. Dbuf, ONE barrier/tile.
// Top wait = unconditional vmcnt(0) (r11's proven drain — r18's counted
// vmcnt(16) raced). exp2-domain softmax, T13 defer-rescale.
// ---------------------------------------------------------------------------
__global__ __launch_bounds__(256, 2) void attn_mfma(
    const u16* __restrict__ Qg,   // [b*SB+tok][DD], pre-scaled by 0.125*log2e
    const u16* __restrict__ Kf,   // fragment-linear
    const u16* __restrict__ Vf,   // fragment-linear
    const float* __restrict__ itg, const float* __restrict__ istg,
    const float* __restrict__ dfg,
    u16* __restrict__ Cg)
{
    const int h  = blockIdx.y;
    const int b  = blockIdx.z;
    const int tid = threadIdx.x;
    const int lane = tid & 63, w = tid >> 6;
    const int l15 = lane & 15, lq = lane >> 4;
    const int qr0 = blockIdx.x * 64 + w * 16;

    __shared__ __align__(16) u16 Ks[2][4096];
    __shared__ __align__(16) u16 Vs[2][4096];
    __shared__ __align__(16) u16 Pb[4][16][72];   // per-wave P transpose buffer

    const bool domaps = (h < 6);
    const float* mapsel = (h < 2) ? itg : (h < 4) ? istg : dfg;
    unsigned moff[4];
    #pragma unroll
    for (int r = 0; r < 4; ++r)
        moff[r] = (unsigned)(b * SB + qr0 + lq * 4 + r) * SB + l15;

    // Q A-frags (held whole kernel)
    s16x8 aq[2];
    {
        const u16* qp = Qg + (size_t)(b * SB + qr0 + l15) * DD + h * 64 + lq * 8;
        aq[0] = *(const s16x8*)qp;
        aq[1] = *(const s16x8*)(qp + 32);
    }

    const u16* KfB = Kf + ((size_t)(b * 8 + h) * 16) * 4096;
    const u16* VfB = Vf + ((size_t)(b * 8 + h) * 16) * 4096;

    // staging: wave w copies segments [w*1024 .. w*1024+1024) of each 4096-elem
    // tile; 2 x gll16 per wave per tensor (64 lanes x 8 elems = 512/call).
    auto stage = [&](int kt, int buf) {
        #pragma unroll
        for (int c2 = 0; c2 < 2; ++c2) {
            const unsigned seg = (unsigned)w * 1024u + c2 * 512u;
            const unsigned off = (unsigned)kt * 4096u + seg + lane * 8u;
            gll16(KfB + off, &Ks[buf][seg]);
            gll16(VfB + off, &Vs[buf][seg]);
        }
    };

    float mc[16];
    auto load_maps = [&](int k0) {
        #pragma unroll
        for (int r = 0; r < 4; ++r)
            #pragma unroll
            for (int nt = 0; nt < 4; ++nt)
                mc[r * 4 + nt] = mapsel[moff[r] + (unsigned)k0 + nt * 16];
    };

    f32x4 ctx[4] = {};
    float m_i[4], lp[4];
    #pragma unroll
    for (int r = 0; r < 4; ++r) { m_i[r] = -3.0e38f; lp[r] = 0.0f; }

    stage(0, 0);
    if (domaps) load_maps(0);

    for (int kt = 0; kt < 16; ++kt) {
        const int buf = kt & 1;
        asm volatile("s_waitcnt vmcnt(0)" ::: "memory");   // my gll landed
        __syncthreads();                                    // everyone's landed
        if (kt + 1 < 16) stage(kt + 1, buf ^ 1);           // async into other buf

        // ---- S = Q K^T (B-frags from LDS, linear & conflict-free) ----
        f32x4 S[4];
        #pragma unroll
        for (int nt = 0; nt < 4; ++nt) {
            s16x8 k0 = *(const s16x8*)&Ks[buf][(nt * 2 + 0) * 512 + lane * 8];
            s16x8 k1 = *(const s16x8*)&Ks[buf][(nt * 2 + 1) * 512 + lane * 8];
            f32x4 s = {};
            s = __builtin_amdgcn_mfma_f32_16x16x32_bf16(aq[0], k0, s, 0, 0, 0);
            s = __builtin_amdgcn_mfma_f32_16x16x32_bf16(aq[1], k1, s, 0, 0, 0);
            S[nt] = s;
        }

        // ---- score modification (exp2 domain), then WAR-prefetch next maps ----
        if (h < 4) {
            #pragma unroll
            for (int nt = 0; nt < 4; ++nt)
                #pragma unroll
                for (int r = 0; r < 4; ++r)
                    S[nt][r] += NEGC2 * mc[r * 4 + nt];
        } else if (h < 6) {
            #pragma unroll
            for (int nt = 0; nt < 4; ++nt)
                #pragma unroll
                for (int r = 0; r < 4; ++r)
                    S[nt][r] *= (1.0f + 5.0f * mc[r * 4 + nt]);
        }
        if (domaps && kt + 1 < 16) load_maps((kt + 1) * 64);

        // ---- online softmax (exp2 domain), T13 defer-rescale ----
        float rm[4];
        #pragma unroll
        for (int r = 0; r < 4; ++r) {
            float v = fmaxf(fmaxf(S[0][r], S[1][r]), fmaxf(S[2][r], S[3][r]));
            rm[r] = row16_max(v);
        }
        float dmax = fmaxf(fmaxf(rm[0] - m_i[0], rm[1] - m_i[1]),
                           fmaxf(rm[2] - m_i[2], rm[3] - m_i[3]));
        if (__any(dmax > THR)) {
            #pragma unroll
            for (int r = 0; r < 4; ++r) {
                float mn = fmaxf(m_i[r], rm[r]);
                float al = __builtin_amdgcn_exp2f(m_i[r] - mn);
                m_i[r] = mn;
                float ls = 0.0f;
                #pragma unroll
                for (int nt = 0; nt < 4; ++nt) {
                    float p = __builtin_amdgcn_exp2f(S[nt][r] - mn);
                    S[nt][r] = p;
                    ls += p;
                }
                lp[r] = lp[r] * al + ls;
                #pragma unroll
                for (int nt = 0; nt < 4; ++nt) ctx[nt][r] *= al;
            }
        } else {
            #pragma unroll
            for (int r = 0; r < 4; ++r) {
                float ls = 0.0f;
                #pragma unroll
                for (int nt = 0; nt < 4; ++nt) {
                    float p = __builtin_amdgcn_exp2f(S[nt][r] - m_i[r]);
                    S[nt][r] = p;
                    ls += p;
                }
                lp[r] += ls;
            }
        }

        // ---- P (C-layout) -> per-wave LDS -> A-layout frags (no barrier) ----
        #pragma unroll
        for (int nt = 0; nt < 4; ++nt)
            #pragma unroll
            for (int r = 0; r < 4; ++r)
                Pb[w][lq * 4 + r][nt * 16 + l15] = f2bf(S[nt][r]);
        s16x8 ap0 = *(const s16x8*)&Pb[w][l15][lq * 8];
        s16x8 ap1 = *(const s16x8*)&Pb[w][l15][32 + lq * 8];

        // ---- ctx += P V (B-frags from LDS) ----
        #pragma unroll
        for (int dvt = 0; dvt < 4; ++dvt) {
            s16x8 v0 = *(const s16x8*)&Vs[buf][(dvt * 2 + 0) * 512 + lane * 8];
            s16x8 v1 = *(const s16x8*)&Vs[buf][(dvt * 2 + 1) * 512 + lane * 8];
            ctx[dvt] = __builtin_amdgcn_mfma_f32_16x16x32_bf16(ap0, v0, ctx[dvt], 0, 0, 0);
            ctx[dvt] = __builtin_amdgcn_mfma_f32_16x16x32_bf16(ap1, v1, ctx[dvt], 0, 0, 0);
        }
    }

    // ---- epilogue: one cross-lane l reduce, normalize, store ----
    #pragma unroll
    for (int r = 0; r < 4; ++r) {
        float l = row16_sum(lp[r]);
        float inv = (l > 0.0f) ? (1.0f / l) : 0.0f;
        #pragma unroll
        for (int dvt = 0; dvt < 4; ++dvt)
            Cg[(size_t)(b * SB + qr0 + lq * 4 + r) * DD + h * 64 + dvt * 16 + l15] =
                f2bf(ctx[dvt][r] * inv);
    }
}

extern "C" void kernel_launch(void* const* d_in, const int* in_sizes, int n_in,
                              void* d_out, int out_size, void* d_ws, size_t ws_size,
                              hipStream_t stream) {
    const float* key   = (const float*)d_in[0];
    const float* value = (const float*)d_in[1];
    const float* query = (const float*)d_in[2];
    const float* itg   = (const float*)d_in[3];
    const float* istg  = (const float*)d_in[4];
    const float* dfg   = (const float*)d_in[5];
    const float* Wq = (const float*)d_in[7];   const float* bq = (const float*)d_in[8];
    const float* Wk = (const float*)d_in[9];   const float* bk = (const float*)d_in[10];
    const float* Wv = (const float*)d_in[11];  const float* bv = (const float*)d_in[12];
    const float* Wo = (const float*)d_in[13];  const float* bo = (const float*)d_in[14];

    const size_t mat = (size_t)8 * SB * DD;
    if (ws_size < 3 * mat * sizeof(u16)) return;

    // slot lifetimes:
    //  A = ws+0     : Kf (repack..attn)
    //  B = ws+mat   : Vf (repack..attn)
    //  C = ws+2*mat : Vn (qkv..repack)  -> Cw (attn..out_gemm)
    //  D = out+0    : Qd (qkv..attn)    -> f32 out low half
    //  E = out+mat  : Kn (qkv..repack)  -> f32 out high half
    u16* A  = (u16*)d_ws;
    u16* Bp = A + mat;
    u16* C  = Bp + mat;
    u16* D  = (u16*)d_out;
    u16* E  = D + mat;

    QKVParams p;
    p.X0 = query; p.X1 = key; p.X2 = value;
    p.W0 = Wq;    p.W1 = Wk;  p.W2 = Wv;
    p.b0 = bq;    p.b1 = bk;  p.b2 = bv;
    p.C0 = D /*Qd*/; p.C1 = E /*Kn*/; p.C2 = C /*Vn*/;
    qkv_gemm<<<dim3(DD / 128, (8 * SB) / 128, 3), 256, 0, stream>>>(p);

    repack_kernel<<<dim3(16, 64), 256, 0, stream>>>(E /*Kn*/, C /*Vn*/, A /*Kf*/, Bp /*Vf*/);

    attn_mfma<<<dim3(SB / 64, 8, 8), 256, 0, stream>>>(D /*Qd*/, A /*Kf*/, Bp /*Vf*/,
                                                       itg, istg, dfg, C /*Cw*/);

    out_gemm<<<dim3(DD / 128, (8 * SB) / 64, 1), 256, 0, stream>>>(C /*Cw*/, Wo, bo, (float*)d_out);
}

// Round 13
// 257.813 us; speedup vs baseline: 1.0625x; 1.0625x over previous
//
#include <hip/hip_runtime.h>

// MultiHeadedAttention (B=8, S=1024, D=512, H=8, DK=DV=64), f32 in/out.
// r20: attn 8-wave blocks — 128 q-rows/block (r15's staging amortization) x
// 16 rows/wave (r19's 68-VGPR state) via 512-thread blocks. 512 blocks =
// 2 blocks/CU but 16 waves/CU (2x TLP of r15). Each wave: 2 gll + 16 map
// loads per tile; 8 waves share one K/V stage. Proven vmcnt(0)+barrier sync.
// GEMMs = r17 (cvt_pk staging, out 64x128).

typedef unsigned short u16;
typedef unsigned u32;
typedef u16 u16x4 __attribute__((ext_vector_type(4)));
typedef u16 u16x8 __attribute__((ext_vector_type(8)));
typedef short s16x8 __attribute__((ext_vector_type(8)));
typedef u32 u32x2 __attribute__((ext_vector_type(2)));
typedef float f32x4 __attribute__((ext_vector_type(4)));

#define SB 1024
#define DD 512
// -1e9 * log2(e): mask penalty in exp2 domain
#define NEGC2 (-1.4426950408889634e9f)
// 0.125 * log2(e): Q scale in exp2 domain
#define QSCALE (0.18033688011112443f)
#define THR 11.5f

__device__ __forceinline__ u16 f2bf(float f) {
    unsigned u = __float_as_uint(f);
    u += 0x7FFFu + ((u >> 16) & 1u);
    return (u16)(u >> 16);
}

// HW packed f32->bf16 (RNE, same rounding as f2bf): lo in [15:0], hi in [31:16]
__device__ __forceinline__ u32 pkbf(float lo, float hi) {
    u32 r;
    asm("v_cvt_pk_bf16_f32 %0, %1, %2" : "=v"(r) : "v"(lo), "v"(hi));
    return r;
}

// global -> LDS direct copy, 16B per lane (wave-uniform LDS base + lane*16)
__device__ __forceinline__ void gll16(const u16* g, u16* l) {
    __builtin_amdgcn_global_load_lds(
        (const __attribute__((address_space(1))) void*)g,
        (__attribute__((address_space(3))) void*)l, 16, 0, 0);
}

// DPP cross-lane (16-lane row) reduce — pure VALU, no LDS pipe.
template<int CTRL>
__device__ __forceinline__ float dppf(float x) {
    return __int_as_float(__builtin_amdgcn_mov_dpp(__float_as_int(x), CTRL, 0xF, 0xF, true));
}
__device__ __forceinline__ float row16_max(float x) {
    x = fmaxf(x, dppf<0xB1>(x));
    x = fmaxf(x, dppf<0x4E>(x));
    x = fmaxf(x, dppf<0x141>(x));
    x = fmaxf(x, dppf<0x140>(x));
    return x;
}
__device__ __forceinline__ float row16_sum(float x) {
    x += dppf<0xB1>(x);
    x += dppf<0x4E>(x);
    x += dppf<0x141>(x);
    x += dppf<0x140>(x);
    return x;
}

// ---------------------------------------------------------------------------
// GEMM body: C[m][n] = (sum_k X[m][k]*W[n][k] + bias[n]) * scale
// Tile BM(M)x128(N), BK=64, 4 waves (wave-tile BM/4 x 128). Double-buffered
// LDS, pitch 64 + XOR swizzle (col ^= (row&7)<<3). ONE barrier/iter.
// XCD swizzle for L2 reuse of X slabs. cvt_pk staging conversion.
// ---------------------------------------------------------------------------
template<bool XF32, bool OUTF32, int BM>
__device__ __forceinline__ void gemm_body(
    const void* __restrict__ Xv, const float* __restrict__ W,
    const float* __restrict__ bias, void* __restrict__ Cv,
    int M, int N, int K, float scale)
{
    __shared__ __align__(16) u16 As[2][BM][64];
    __shared__ __align__(16) u16 Bs[2][128][64];
    const int tid  = threadIdx.x;
    const int lane = tid & 63, wave = tid >> 6;
    const int l15 = lane & 15, lq = lane >> 4;

    const int l   = blockIdx.x + gridDim.x * blockIdx.y;
    const int xcd = l & 7, j = l >> 3;
    const int nb  = N / 128;
    const int m0  = (xcd * (M / BM / 8) + (j / nb)) * BM;
    const int n0  = (j % nb) * 128;

    constexpr int XI32 = BM / 16;   // f32-X staging passes (16 rows each)
    constexpr int XI16 = BM / 32;   // bf16-X staging passes (32 rows each)
    constexpr int MT   = BM / 64;   // 16-row MFMA tiles per wave

    // staging index precompute
    int xr32[XI32], xc32_, xr16[XI16], xc16_, wr_[8], wc_;
    xc32_ = (tid & 15) * 4;
    xc16_ = (tid & 7) * 8;
    wc_   = (tid & 15) * 4;
    #pragma unroll
    for (int i = 0; i < XI32; ++i) xr32[i] = i * 16 + (tid >> 4);
    #pragma unroll
    for (int i = 0; i < XI16; ++i) xr16[i] = i * 32 + (tid >> 3);
    #pragma unroll
    for (int i = 0; i < 8; ++i)    wr_[i]  = i * 16 + (tid >> 4);

    f32x4 xa32[XI32];  u16x8 xa16[XI16];  f32x4 wa[8];
    auto load_slab = [&](int k0) {
        if (XF32) {
            #pragma unroll
            for (int i = 0; i < XI32; ++i)
                xa32[i] = *(const f32x4*)((const float*)Xv + (size_t)(m0 + xr32[i]) * K + k0 + xc32_);
        } else {
            #pragma unroll
            for (int i = 0; i < XI16; ++i)
                xa16[i] = *(const u16x8*)((const u16*)Xv + (size_t)(m0 + xr16[i]) * K + k0 + xc16_);
        }
        #pragma unroll
        for (int i = 0; i < 8; ++i)
            wa[i] = *(const f32x4*)(W + (size_t)(n0 + wr_[i]) * K + k0 + wc_);
    };
    auto write_lds = [&](int buf) {
        if (XF32) {
            #pragma unroll
            for (int i = 0; i < XI32; ++i) {
                u32x2 t;
                t[0] = pkbf(xa32[i][0], xa32[i][1]);
                t[1] = pkbf(xa32[i][2], xa32[i][3]);
                *(u32x2*)&As[buf][xr32[i]][xc32_ ^ ((xr32[i] & 7) << 3)] = t;
            }
        } else {
            #pragma unroll
            for (int i = 0; i < XI16; ++i)
                *(u16x8*)&As[buf][xr16[i]][xc16_ ^ ((xr16[i] & 7) << 3)] = xa16[i];
        }
        #pragma unroll
        for (int i = 0; i < 8; ++i) {
            u32x2 t;
            t[0] = pkbf(wa[i][0], wa[i][1]);
            t[1] = pkbf(wa[i][2], wa[i][3]);
            *(u32x2*)&Bs[buf][wr_[i]][wc_ ^ ((wr_[i] & 7) << 3)] = t;
        }
    };

    f32x4 acc[MT][8] = {};
    load_slab(0);
    const int steps = K / 64;
    for (int kt = 0; kt < steps; ++kt) {
        const int buf = kt & 1;
        write_lds(buf);            // slab kt (regs from iter kt-1); buffer unread this iter
        __syncthreads();
        if (kt + 1 < steps) load_slab((kt + 1) * 64);

        #pragma unroll
        for (int ks = 0; ks < 2; ++ks) {
            const int kc = ks * 32 + lq * 8;
            s16x8 af[MT], bf[8];
            #pragma unroll
            for (int mt = 0; mt < MT; ++mt) {
                const int ar = wave * (BM / 4) + mt * 16 + l15;
                af[mt] = *(const s16x8*)&As[buf][ar][kc ^ ((ar & 7) << 3)];
            }
            #pragma unroll
            for (int nt = 0; nt < 8; ++nt) {
                const int br = nt * 16 + l15;
                bf[nt] = *(const s16x8*)&Bs[buf][br][kc ^ ((br & 7) << 3)];
            }
            #pragma unroll
            for (int mt = 0; mt < MT; ++mt)
                #pragma unroll
                for (int nt = 0; nt < 8; ++nt)
                    acc[mt][nt] = __builtin_amdgcn_mfma_f32_16x16x32_bf16(
                        af[mt], bf[nt], acc[mt][nt], 0, 0, 0);
        }
    }

    float bb[8];
    #pragma unroll
    for (int nt = 0; nt < 8; ++nt) bb[nt] = bias[n0 + nt * 16 + l15];
    #pragma unroll
    for (int mt = 0; mt < MT; ++mt) {
        #pragma unroll
        for (int r = 0; r < 4; ++r) {
            const size_t row = (size_t)(m0 + wave * (BM / 4) + mt * 16 + lq * 4 + r);
            #pragma unroll
            for (int nt = 0; nt < 8; ++nt) {
                float v = (acc[mt][nt][r] + bb[nt]) * scale;
                const size_t col = n0 + nt * 16 + l15;
                if (OUTF32) ((float*)Cv)[row * N + col] = v;
                else        ((u16*)Cv)[row * N + col] = f2bf(v);
            }
        }
    }
}

struct QKVParams {
    const float *X0, *X1, *X2;
    const float *W0, *W1, *W2;
    const float *b0, *b1, *b2;
    u16 *C0, *C1, *C2;
};

// fused Q/K/V projections: blockIdx.z selects the sub-GEMM
__global__ __launch_bounds__(256, 2) void qkv_gemm(QKVParams p) {
    const int z = blockIdx.z;
    const float* X = (z == 0) ? p.X0 : (z == 1) ? p.X1 : p.X2;
    const float* W = (z == 0) ? p.W0 : (z == 1) ? p.W1 : p.W2;
    const float* b = (z == 0) ? p.b0 : (z == 1) ? p.b1 : p.b2;
    u16* C = (z == 0) ? p.C0 : (z == 1) ? p.C1 : p.C2;
    const float scale = (z == 0) ? QSCALE : 1.0f;   // Q in exp2 domain
    gemm_body<true, false, 128>(X, W, b, C, 8 * SB, DD, DD, scale);
}

// 64x128 tile: 512 blocks, 48KB LDS -> up to 3 blocks/CU
__global__ __launch_bounds__(256, 2) void out_gemm(
    const u16* __restrict__ X, const float* __restrict__ W,
    const float* __restrict__ bias, float* __restrict__ C) {
    gemm_body<false, true, 64>(X, W, bias, C, 8 * SB, DD, DD, 1.0f);
}

// ---------------------------------------------------------------------------
// repack: K,V (bf16, [b*SB+tok][h*64+d] row-major) -> fragment-linear layouts.
// Frag tile = 512 elems (64 lanes x 8): offset ((bh*16+kb)*8 + nt*2+ks)*512 + lane*8.
//   Kf elem(lane,e) = K[tok=kb*64+nt*16+(lane&15)][d =ks*32+(lane>>4)*8+e]
//   Vf elem(lane,e) = V[tok=kb*64+ks*32+(lane>>4)*8+e][dv=nt*16+(lane&15)]
// ---------------------------------------------------------------------------
__global__ __launch_bounds__(256) void repack_kernel(
    const u16* __restrict__ Kn, const u16* __restrict__ Vn,
    u16* __restrict__ Kf, u16* __restrict__ Vf)
{
    __shared__ u16 Ls[2][64][72];
    const int t = threadIdx.x;
    const int kb = blockIdx.x;          // 0..15
    const int bh = blockIdx.y;          // 0..63
    const int b = bh >> 3, h = bh & 7;
    const int r = t >> 2, c = (t & 3) * 16;

    const size_t srow = (size_t)(b * SB + kb * 64 + r) * DD + h * 64 + c;
    *(u16x8*)&Ls[0][r][c]     = *(const u16x8*)(Kn + srow);
    *(u16x8*)&Ls[0][r][c + 8] = *(const u16x8*)(Kn + srow + 8);
    *(u16x8*)&Ls[1][r][c]     = *(const u16x8*)(Vn + srow);
    *(u16x8*)&Ls[1][r][c + 8] = *(const u16x8*)(Vn + srow + 8);
    __syncthreads();

    const int lane = t & 63, w = t >> 6;
    const int l15 = lane & 15, lq = lane >> 4;
    const size_t tb = ((size_t)bh * 16 + kb) * 4096 + lane * 8;
    #pragma unroll
    for (int i = 0; i < 2; ++i) {
        const int t2 = w * 2 + i;          // 0..7 = nt*2+ks
        const int nt = t2 >> 1, ks = t2 & 1;
        u16x8 ko = *(const u16x8*)&Ls[0][nt * 16 + l15][ks * 32 + lq * 8];
        *(u16x8*)(Kf + tb + t2 * 512) = ko;
        u16x8 vo;
        #pragma unroll
        for (int e = 0; e < 8; ++e) vo[e] = Ls[1][ks * 32 + lq * 8 + e][nt * 16 + l15];
        *(u16x8*)(Vf + tb + t2 * 512) = vo;
    }
}

// ---------------------------------------------------------------------------
// Flash attention. Grid (8,8,8) = 512 blocks, 512 thr / 8 waves; 128
// q-rows/block, wave w owns 16 rows (ONE 16-row MFMA tile). 2 blocks/CU =
// 16 waves/CU (2x r15's TLP). K/V staged ONCE per block per tile (8 waves
// share): each wave issues 1 gll per tensor (seg = w*512). Dbuf, ONE
// barrier/tile, unconditional vmcnt(0) (proven r19). exp2 softmax, T13.
// ---------------------------------------------------------------------------
__global__ __launch_bounds__(512, 2) void attn_mfma(
    const u16* __restrict__ Qg,   // [b*SB+tok][DD], pre-scaled by 0.125*log2e
    const u16* __restrict__ Kf,   // fragment-linear
    const u16* __restrict__ Vf,   // fragment-linear
    const float* __restrict__ itg, const float* __restrict__ istg,
    const float* __restrict__ dfg,
    u16* __restrict__ Cg)
{
    const int h  = blockIdx.y;
    const int b  = blockIdx.z;
    const int tid = threadIdx.x;
    const int lane = tid & 63, w = tid >> 6;     // w in 0..7
    const int l15 = lane & 15, lq = lane >> 4;
    const int qr0 = blockIdx.x * 128 + w * 16;

    __shared__ __align__(16) u16 Ks[2][4096];
    __shared__ __align__(16) u16 Vs[2][4096];
    __shared__ __align__(16) u16 Pb[8][16][72];   // per-wave P transpose buffer

    const bool domaps = (h < 6);
    const float* mapsel = (h < 2) ? itg : (h < 4) ? istg : dfg;
    unsigned moff[4];
    #pragma unroll
    for (int r = 0; r < 4; ++r)
        moff[r] = (unsigned)(b * SB + qr0 + lq * 4 + r) * SB + l15;

    // Q A-frags (held whole kernel)
    s16x8 aq[2];
    {
        const u16* qp = Qg + (size_t)(b * SB + qr0 + l15) * DD + h * 64 + lq * 8;
        aq[0] = *(const s16x8*)qp;
        aq[1] = *(const s16x8*)(qp + 32);
    }

    const u16* KfB = Kf + ((size_t)(b * 8 + h) * 16) * 4096;
    const u16* VfB = Vf + ((size_t)(b * 8 + h) * 16) * 4096;

    // staging: wave w copies segment [w*512 .. w*512+512) of each 4096-elem
    // tile; ONE gll16 per tensor per wave (64 lanes x 8 elems = 512).
    auto stage = [&](int kt, int buf) {
        const unsigned seg = (unsigned)w * 512u;
        const unsigned off = (unsigned)kt * 4096u + seg + lane * 8u;
        gll16(KfB + off, &Ks[buf][seg]);
        gll16(VfB + off, &Vs[buf][seg]);
    };

    float mc[16];
    auto load_maps = [&](int k0) {
        #pragma unroll
        for (int r = 0; r < 4; ++r)
            #pragma unroll
            for (int nt = 0; nt < 4; ++nt)
                mc[r * 4 + nt] = mapsel[moff[r] + (unsigned)k0 + nt * 16];
    };

    f32x4 ctx[4] = {};
    float m_i[4], lp[4];
    #pragma unroll
    for (int r = 0; r < 4; ++r) { m_i[r] = -3.0e38f; lp[r] = 0.0f; }

    stage(0, 0);
    if (domaps) load_maps(0);

    for (int kt = 0; kt < 16; ++kt) {
        const int buf = kt & 1;
        asm volatile("s_waitcnt vmcnt(0)" ::: "memory");   // my gll landed
        __syncthreads();                                    // everyone's landed
        if (kt + 1 < 16) stage(kt + 1, buf ^ 1);           // async into other buf

        // ---- S = Q K^T (B-frags from LDS, linear & conflict-free) ----
        f32x4 S[4];
        #pragma unroll
        for (int nt = 0; nt < 4; ++nt) {
            s16x8 k0 = *(const s16x8*)&Ks[buf][(nt * 2 + 0) * 512 + lane * 8];
            s16x8 k1 = *(const s16x8*)&Ks[buf][(nt * 2 + 1) * 512 + lane * 8];
            f32x4 s = {};
            s = __builtin_amdgcn_mfma_f32_16x16x32_bf16(aq[0], k0, s, 0, 0, 0);
            s = __builtin_amdgcn_mfma_f32_16x16x32_bf16(aq[1], k1, s, 0, 0, 0);
            S[nt] = s;
        }

        // ---- score modification (exp2 domain), then WAR-prefetch next maps ----
        if (h < 4) {
            #pragma unroll
            for (int nt = 0; nt < 4; ++nt)
                #pragma unroll
                for (int r = 0; r < 4; ++r)
                    S[nt][r] += NEGC2 * mc[r * 4 + nt];
        } else if (h < 6) {
            #pragma unroll
            for (int nt = 0; nt < 4; ++nt)
                #pragma unroll
                for (int r = 0; r < 4; ++r)
                    S[nt][r] *= (1.0f + 5.0f * mc[r * 4 + nt]);
        }
        if (domaps && kt + 1 < 16) load_maps((kt + 1) * 64);

        // ---- online softmax (exp2 domain), T13 defer-rescale ----
        float rm[4];
        #pragma unroll
        for (int r = 0; r < 4; ++r) {
            float v = fmaxf(fmaxf(S[0][r], S[1][r]), fmaxf(S[2][r], S[3][r]));
            rm[r] = row16_max(v);
        }
        float dmax = fmaxf(fmaxf(rm[0] - m_i[0], rm[1] - m_i[1]),
                           fmaxf(rm[2] - m_i[2], rm[3] - m_i[3]));
        if (__any(dmax > THR)) {
            #pragma unroll
            for (int r = 0; r < 4; ++r) {
                float mn = fmaxf(m_i[r], rm[r]);
                float al = __builtin_amdgcn_exp2f(m_i[r] - mn);
                m_i[r] = mn;
                float ls = 0.0f;
                #pragma unroll
                for (int nt = 0; nt < 4; ++nt) {
                    float p = __builtin_amdgcn_exp2f(S[nt][r] - mn);
                    S[nt][r] = p;
                    ls += p;
                }
                lp[r] = lp[r] * al + ls;
                #pragma unroll
                for (int nt = 0; nt < 4; ++nt) ctx[nt][r] *= al;
            }
        } else {
            #pragma unroll
            for (int r = 0; r < 4; ++r) {
                float ls = 0.0f;
                #pragma unroll
                for (int nt = 0; nt < 4; ++nt) {
                    float p = __builtin_amdgcn_exp2f(S[nt][r] - m_i[r]);
                    S[nt][r] = p;
                    ls += p;
                }
                lp[r] += ls;
            }
        }

        // ---- P (C-layout) -> per-wave LDS -> A-layout frags (no barrier) ----
        #pragma unroll
        for (int nt = 0; nt < 4; ++nt)
            #pragma unroll
            for (int r = 0; r < 4; ++r)
                Pb[w][lq * 4 + r][nt * 16 + l15] = f2bf(S[nt][r]);
        s16x8 ap0 = *(const s16x8*)&Pb[w][l15][lq * 8];
        s16x8 ap1 = *(const s16x8*)&Pb[w][l15][32 + lq * 8];

        // ---- ctx += P V (B-frags from LDS) ----
        #pragma unroll
        for (int dvt = 0; dvt < 4; ++dvt) {
            s16x8 v0 = *(const s16x8*)&Vs[buf][(dvt * 2 + 0) * 512 + lane * 8];
            s16x8 v1 = *(const s16x8*)&Vs[buf][(dvt * 2 + 1) * 512 + lane * 8];
            ctx[dvt] = __builtin_amdgcn_mfma_f32_16x16x32_bf16(ap0, v0, ctx[dvt], 0, 0, 0);
            ctx[dvt] = __builtin_amdgcn_mfma_f32_16x16x32_bf16(ap1, v1, ctx[dvt], 0, 0, 0);
        }
    }

    // ---- epilogue: one cross-lane l reduce, normalize, store ----
    #pragma unroll
    for (int r = 0; r < 4; ++r) {
        float l = row16_sum(lp[r]);
        float inv = (l > 0.0f) ? (1.0f / l) : 0.0f;
        #pragma unroll
        for (int dvt = 0; dvt < 4; ++dvt)
            Cg[(size_t)(b * SB + qr0 + lq * 4 + r) * DD + h * 64 + dvt * 16 + l15] =
                f2bf(ctx[dvt][r] * inv);
    }
}

extern "C" void kernel_launch(void* const* d_in, const int* in_sizes, int n_in,
                              void* d_out, int out_size, void* d_ws, size_t ws_size,
                              hipStream_t stream) {
    const float* key   = (const float*)d_in[0];
    const float* value = (const float*)d_in[1];
    const float* query = (const float*)d_in[2];
    const float* itg   = (const float*)d_in[3];
    const float* istg  = (const float*)d_in[4];
    const float* dfg   = (const float*)d_in[5];
    const float* Wq = (const float*)d_in[7];   const float* bq = (const float*)d_in[8];
    const float* Wk = (const float*)d_in[9];   const float* bk = (const float*)d_in[10];
    const float* Wv = (const float*)d_in[11];  const float* bv = (const float*)d_in[12];
    const float* Wo = (const float*)d_in[13];  const float* bo = (const float*)d_in[14];

    const size_t mat = (size_t)8 * SB * DD;
    if (ws_size < 3 * mat * sizeof(u16)) return;

    // slot lifetimes:
    //  A = ws+0     : Kf (repack..attn)
    //  B = ws+mat   : Vf (repack..attn)
    //  C = ws+2*mat : Vn (qkv..repack)  -> Cw (attn..out_gemm)
    //  D = out+0    : Qd (qkv..attn)    -> f32 out low half
    //  E = out+mat  : Kn (qkv..repack)  -> f32 out high half
    u16* A  = (u16*)d_ws;
    u16* Bp = A + mat;
    u16* C  = Bp + mat;
    u16* D  = (u16*)d_out;
    u16* E  = D + mat;

    QKVParams p;
    p.X0 = query; p.X1 = key; p.X2 = value;
    p.W0 = Wq;    p.W1 = Wk;  p.W2 = Wv;
    p.b0 = bq;    p.b1 = bk;  p.b2 = bv;
    p.C0 = D /*Qd*/; p.C1 = E /*Kn*/; p.C2 = C /*Vn*/;
    qkv_gemm<<<dim3(DD / 128, (8 * SB) / 128, 3), 256, 0, stream>>>(p);

    repack_kernel<<<dim3(16, 64), 256, 0, stream>>>(E /*Kn*/, C /*Vn*/, A /*Kf*/, Bp /*Vf*/);

    attn_mfma<<<dim3(SB / 128, 8, 8), 512, 0, stream>>>(D /*Qd*/, A /*Kf*/, Bp /*Vf*/,
                                                        itg, istg, dfg, C /*Cw*/);

    out_gemm<<<dim3(DD / 128, (8 * SB) / 64, 1), 256, 0, stream>>>(C /*Cw*/, Wo, bo, (float*)d_out);
}